// Round 4
// baseline (584.998 us; speedup 1.0000x reference)
//
#include <hip/hip_runtime.h>
#include <math.h>

// Problem constants (S, B, D from reference).
#define S_LEN    2048
#define BATCH    32
#define DIM      1024
#define P_CHUNKS 32                 // seq chunks (blocks per batch)
#define CHUNK    (S_LEN / P_CHUNKS) // 64 rows per block
#define ROWS_PER_WAVE (CHUNK / 4)   // 16 rows per wave

// ---------------------------------------------------------------------------
// Skinny GEMM: out[b][d] = act( sum_k A[b][k] * W[d][k] ), b in [0,32).
// One wave per output column d (4 waves/block -> grid = Dout/4 blocks).
// A (32 x K) is staged in LDS in 256-wide K tiles, double-buffered; the
// next tile's staging registers AND the next W fragment are prefetched
// during compute so global loads stay in flight across the barrier.
// act: 0 = identity, 1 = tanh.
// cnt: if non-null, block 0 zeroes 32 per-batch arrival counters (used by
//      the downstream attn kernel's last-block combine). Free piggyback.
// ---------------------------------------------------------------------------
__global__ __launch_bounds__(256) void gemm_skinny(
    const float* __restrict__ A, const float* __restrict__ W,
    float* __restrict__ out, int K, int Dout, int act,
    unsigned* __restrict__ cnt)
{
    __shared__ __align__(16) float At[2][32 * 256];  // 2 x 32 KiB

    const int t    = threadIdx.x;
    const int lane = t & 63;
    const int wid  = t >> 6;
    const int d    = blockIdx.x * 4 + wid;

    if (cnt && blockIdx.x == 0 && t < BATCH) cnt[t] = 0u;

    float acc[32];
#pragma unroll
    for (int b = 0; b < 32; ++b) acc[b] = 0.0f;

    // Preload tile 0 staging regs + this wave's W fragment for tile 0.
    float4 sreg[8];
#pragma unroll
    for (int i = 0; i < 8; ++i) {
        int f4id = t + i * 256;
        int bb   = f4id >> 6;       // row (batch)
        int c4   = f4id & 63;       // float4 column within tile
        sreg[i] = ((const float4*)(A + (size_t)bb * K))[c4];
    }
    float4 w4 = ((const float4*)(W + (size_t)d * K))[lane];

    int buf = 0;
    for (int k0 = 0; k0 < K; k0 += 256) {
        // Commit staged regs into LDS[buf].
#pragma unroll
        for (int i = 0; i < 8; ++i) {
            int f4id = t + i * 256;
            int bb   = f4id >> 6;
            int c4   = f4id & 63;
            ((float4*)At[buf])[bb * 64 + c4] = sreg[i];
        }
        __syncthreads();

        float4 w4c = w4;
        // Prefetch next tile (regs + W) while we compute this one.
        if (k0 + 256 < K) {
            const int k1 = k0 + 256;
#pragma unroll
            for (int i = 0; i < 8; ++i) {
                int f4id = t + i * 256;
                int bb   = f4id >> 6;
                int c4   = f4id & 63;
                sreg[i] = ((const float4*)(A + (size_t)bb * K + k1))[c4];
            }
            w4 = ((const float4*)(W + (size_t)d * K + k1))[lane];
        }

#pragma unroll
        for (int b = 0; b < 32; ++b) {
            float4 a4 = ((const float4*)At[buf])[b * 64 + lane];
            acc[b] = fmaf(w4c.x, a4.x, acc[b]);
            acc[b] = fmaf(w4c.y, a4.y, acc[b]);
            acc[b] = fmaf(w4c.z, a4.z, acc[b]);
            acc[b] = fmaf(w4c.w, a4.w, acc[b]);
        }
        buf ^= 1;
        // Single barrier per tile is safe: iteration i+1 writes the OTHER
        // buffer, and barrier_i guarantees all waves finished reading it.
    }

    // Reduce each acc[b] across the 64 lanes; lane b keeps batch b's result.
    float mine = 0.0f;
#pragma unroll
    for (int b = 0; b < 32; ++b) {
        float v = acc[b];
#pragma unroll
        for (int off = 32; off > 0; off >>= 1) v += __shfl_xor(v, off, 64);
        if (lane == b) mine = v;
    }
    if (lane < 32) {
        float o = act ? tanhf(mine) : mine;
        out[(size_t)lane * Dout + d] = o;
    }
}

// ---------------------------------------------------------------------------
// Flash-style fused logits + online softmax + weighted-sum partials,
// PLUS in-kernel final combine by the last-arriving block of each batch.
//
// Hot loop: each of the 4 waves owns 16 seq rows and the full 1024-wide
// feature dim (4 x float4 per lane); dot reduce is 6 in-wave shuffles, no
// barriers. Defer-rescale (THR=8): post-reduce logit is wave-uniform, so
// the rescale branch is uniform and rare; P-terms bounded by e^8 (f32
// accumulates safely; renormalized at combine).
//
// Epilogue: 4 wave-partials -> 1 chunk-partial in LDS; chunk partial is
// stored; then threadfence + per-batch acq_rel counter. The 32nd block of
// batch b (L2-hot pacc) merges all 32 chunk-partials and writes cat[b].
// ---------------------------------------------------------------------------
__global__ __launch_bounds__(256, 4) void attn_partial(
    const float* __restrict__ input, const float* __restrict__ semi,
    float* __restrict__ pacc, float* __restrict__ pm, float* __restrict__ pl,
    const float* __restrict__ h, float* __restrict__ cat,
    unsigned* __restrict__ cnt)
{
    const int p    = blockIdx.x;   // seq chunk
    const int b    = blockIdx.y;   // batch
    const int t    = threadIdx.x;
    const int lane = t & 63;
    const int w    = t >> 6;
    const int s0   = p * CHUNK + w * ROWS_PER_WAVE;

    __shared__ __align__(16) float accs[4][DIM];   // 16 KiB
    __shared__ float smw[4], slw[4];
    __shared__ unsigned is_last;
    __shared__ float fsc[P_CHUNKS];
    __shared__ float Linv;

    // semi[b] fragment: 4 float4 per lane covering all 1024 features.
    const float4* sp = (const float4*)(semi + (size_t)b * DIM);
    const float4 sm0 = sp[lane];
    const float4 sm1 = sp[lane + 64];
    const float4 sm2 = sp[lane + 128];
    const float4 sm3 = sp[lane + 192];

    const float4* rp = (const float4*)(input + ((size_t)s0 * BATCH + b) * DIM);
    const size_t rstride = (size_t)BATCH * DIM / 4;  // 8192 float4 / seq row

    float m = -INFINITY, l = 0.0f;
    float4 a0 = make_float4(0.f, 0.f, 0.f, 0.f);
    float4 a1 = a0, a2 = a0, a3 = a0;

    // Prefetch row 0.
    float4 x0 = rp[lane], x1 = rp[lane + 64], x2 = rp[lane + 128], x3 = rp[lane + 192];

#pragma unroll 1
    for (int j = 0; j < ROWS_PER_WAVE; ++j) {
        const float4 c0 = x0, c1 = x1, c2 = x2, c3 = x3;
        if (j + 1 < ROWS_PER_WAVE) {
            const float4* np = rp + (size_t)(j + 1) * rstride;
            x0 = np[lane];       x1 = np[lane + 64];
            x2 = np[lane + 128]; x3 = np[lane + 192];
        }

        // 16-element partial dot for this lane.
        float pd = c0.x * sm0.x;
        pd = fmaf(c0.y, sm0.y, pd); pd = fmaf(c0.z, sm0.z, pd); pd = fmaf(c0.w, sm0.w, pd);
        pd = fmaf(c1.x, sm1.x, pd); pd = fmaf(c1.y, sm1.y, pd);
        pd = fmaf(c1.z, sm1.z, pd); pd = fmaf(c1.w, sm1.w, pd);
        pd = fmaf(c2.x, sm2.x, pd); pd = fmaf(c2.y, sm2.y, pd);
        pd = fmaf(c2.z, sm2.z, pd); pd = fmaf(c2.w, sm2.w, pd);
        pd = fmaf(c3.x, sm3.x, pd); pd = fmaf(c3.y, sm3.y, pd);
        pd = fmaf(c3.z, sm3.z, pd); pd = fmaf(c3.w, sm3.w, pd);

        // Full-wave butterfly: every lane ends with the row logit (uniform).
#pragma unroll
        for (int off = 32; off > 0; off >>= 1) pd += __shfl_xor(pd, off, 64);

        // Defer-rescale online softmax (wave-uniform branch).
        if (pd > m + 8.0f) {
            const float sc = __expf(m - pd);   // exp(-inf) = 0 on first row
            a0.x *= sc; a0.y *= sc; a0.z *= sc; a0.w *= sc;
            a1.x *= sc; a1.y *= sc; a1.z *= sc; a1.w *= sc;
            a2.x *= sc; a2.y *= sc; a2.z *= sc; a2.w *= sc;
            a3.x *= sc; a3.y *= sc; a3.z *= sc; a3.w *= sc;
            l *= sc;
            m = pd;
        }
        const float f = __expf(pd - m);        // bounded by e^8
        a0.x = fmaf(f, c0.x, a0.x); a0.y = fmaf(f, c0.y, a0.y);
        a0.z = fmaf(f, c0.z, a0.z); a0.w = fmaf(f, c0.w, a0.w);
        a1.x = fmaf(f, c1.x, a1.x); a1.y = fmaf(f, c1.y, a1.y);
        a1.z = fmaf(f, c1.z, a1.z); a1.w = fmaf(f, c1.w, a1.w);
        a2.x = fmaf(f, c2.x, a2.x); a2.y = fmaf(f, c2.y, a2.y);
        a2.z = fmaf(f, c2.z, a2.z); a2.w = fmaf(f, c2.w, a2.w);
        a3.x = fmaf(f, c3.x, a3.x); a3.y = fmaf(f, c3.y, a3.y);
        a3.z = fmaf(f, c3.z, a3.z); a3.w = fmaf(f, c3.w, a3.w);
        l += f;
    }

    // ---- block-level combine: 4 wave-partials -> 1 chunk-partial ----
    float4* as = (float4*)accs[w];
    as[lane]       = a0;
    as[lane + 64]  = a1;
    as[lane + 128] = a2;
    as[lane + 192] = a3;
    if (lane == 0) { smw[w] = m; slw[w] = l; }
    __syncthreads();

    const float M  = fmaxf(fmaxf(smw[0], smw[1]), fmaxf(smw[2], smw[3]));
    const float f0 = __expf(smw[0] - M);
    const float f1 = __expf(smw[1] - M);
    const float f2 = __expf(smw[2] - M);
    const float f3 = __expf(smw[3] - M);

    const float4 r0 = ((const float4*)accs[0])[t];
    const float4 r1 = ((const float4*)accs[1])[t];
    const float4 r2 = ((const float4*)accs[2])[t];
    const float4 r3 = ((const float4*)accs[3])[t];
    float4 o;
    o.x = fmaf(f3, r3.x, fmaf(f2, r2.x, fmaf(f1, r1.x, f0 * r0.x)));
    o.y = fmaf(f3, r3.y, fmaf(f2, r2.y, fmaf(f1, r1.y, f0 * r0.y)));
    o.z = fmaf(f3, r3.z, fmaf(f2, r2.z, fmaf(f1, r1.z, f0 * r0.z)));
    o.w = fmaf(f3, r3.w, fmaf(f2, r2.w, fmaf(f1, r1.w, f0 * r0.w)));

    ((float4*)(pacc + ((size_t)b * P_CHUNKS + p) * DIM))[t] = o;
    if (t == 0) {
        pm[b * P_CHUNKS + p] = M;
        pl[b * P_CHUNKS + p] =
            fmaf(f3, slw[3], fmaf(f2, slw[2], fmaf(f1, slw[1], f0 * slw[0])));
    }

    // ---- last-block-per-batch final combine ----
    __threadfence();          // every thread: make its stores device-visible
    __syncthreads();          // all fences in this block done
    if (t == 0) {
        unsigned old = __hip_atomic_fetch_add(&cnt[b], 1u,
                         __ATOMIC_ACQ_REL, __HIP_MEMORY_SCOPE_AGENT);
        is_last = (old == P_CHUNKS - 1) ? 1u : 0u;
    }
    __syncthreads();          // is_last is block-uniform
    if (!is_last) return;

    // This block is the 32nd arriver for batch b: all chunk partials of
    // batch b are globally visible (acq_rel chain). Merge them.
    if (t < P_CHUNKS) {
        const float mv = pm[b * P_CHUNKS + t];
        const float lv = pl[b * P_CHUNKS + t];
        float mx = mv;
#pragma unroll
        for (int off = 16; off > 0; off >>= 1)
            mx = fmaxf(mx, __shfl_xor(mx, off, 64));   // lanes 0-31 only
        const float fsv = __expf(mv - mx);
        fsc[t] = fsv;
        float L = lv * fsv;
#pragma unroll
        for (int off = 16; off > 0; off >>= 1) L += __shfl_xor(L, off, 64);
        if (t == 0) Linv = 1.0f / L;
    }
    __syncthreads();

    // Thread t owns float4 slot t of the 1024-dim output (256*4 = 1024).
    const float4* pb4 = (const float4*)(pacc + (size_t)b * P_CHUNKS * DIM);
    float4 s0v = make_float4(0.f, 0.f, 0.f, 0.f);
    float4 s1v = s0v, s2v = s0v, s3v = s0v;
#pragma unroll
    for (int pp = 0; pp < P_CHUNKS; pp += 4) {
        const float4 v0 = pb4[(size_t)(pp + 0) * (DIM / 4) + t];
        const float4 v1 = pb4[(size_t)(pp + 1) * (DIM / 4) + t];
        const float4 v2 = pb4[(size_t)(pp + 2) * (DIM / 4) + t];
        const float4 v3 = pb4[(size_t)(pp + 3) * (DIM / 4) + t];
        const float g0 = fsc[pp + 0], g1 = fsc[pp + 1];
        const float g2 = fsc[pp + 2], g3 = fsc[pp + 3];
        s0v.x = fmaf(g0, v0.x, s0v.x); s0v.y = fmaf(g0, v0.y, s0v.y);
        s0v.z = fmaf(g0, v0.z, s0v.z); s0v.w = fmaf(g0, v0.w, s0v.w);
        s1v.x = fmaf(g1, v1.x, s1v.x); s1v.y = fmaf(g1, v1.y, s1v.y);
        s1v.z = fmaf(g1, v1.z, s1v.z); s1v.w = fmaf(g1, v1.w, s1v.w);
        s2v.x = fmaf(g2, v2.x, s2v.x); s2v.y = fmaf(g2, v2.y, s2v.y);
        s2v.z = fmaf(g2, v2.z, s2v.z); s2v.w = fmaf(g2, v2.w, s2v.w);
        s3v.x = fmaf(g3, v3.x, s3v.x); s3v.y = fmaf(g3, v3.y, s3v.y);
        s3v.z = fmaf(g3, v3.z, s3v.z); s3v.w = fmaf(g3, v3.w, s3v.w);
    }
    float4 sum;
    sum.x = ((s0v.x + s1v.x) + (s2v.x + s3v.x)) * Linv;
    sum.y = ((s0v.y + s1v.y) + (s2v.y + s3v.y)) * Linv;
    sum.z = ((s0v.z + s1v.z) + (s2v.z + s3v.z)) * Linv;
    sum.w = ((s0v.w + s1v.w) + (s2v.w + s3v.w)) * Linv;

    float4* cat4 = (float4*)(cat + (size_t)b * (2 * DIM));
    cat4[t]             = sum;                                       // s_tilde
    cat4[DIM / 4 + t]   = ((const float4*)(h + (size_t)b * DIM))[t]; // h copy
}

// ---------------------------------------------------------------------------
extern "C" void kernel_launch(void* const* d_in, const int* in_sizes, int n_in,
                              void* d_out, int out_size, void* d_ws, size_t ws_size,
                              hipStream_t stream)
{
    const float* input = (const float*)d_in[0];  // [S, B, D]
    const float* h     = (const float*)d_in[1];  // [B, D]
    const float* Wi    = (const float*)d_in[2];  // [D, D]
    const float* Wo    = (const float*)d_in[3];  // [D, 2D]
    float* out = (float*)d_out;                  // [B, D]

    // Workspace carve (floats): semi | pacc | pm | pl | cat | cnt (~4.4 MiB)
    float* ws   = (float*)d_ws;
    float* semi = ws;                                       // 32*1024
    float* pacc = semi + 32 * 1024;                         // 32*32*1024
    float* pm   = pacc + (size_t)32 * P_CHUNKS * 1024;      // 32*32
    float* pl   = pm + 32 * P_CHUNKS;                       // 32*32
    float* cat  = pl + 32 * P_CHUNKS;                       // 32*2048
    unsigned* cnt = (unsigned*)(cat + 32 * 2 * DIM);        // 32 counters

    // 1) semi = h @ Wi.T  (K=1024, Dout=1024); also zeroes cnt[0:32].
    hipLaunchKernelGGL(gemm_skinny, dim3(256), dim3(256), 0, stream,
                       h, Wi, semi, 1024, 1024, 0, cnt);
    // 2) fused logits + online softmax + partials + last-block combine
    hipLaunchKernelGGL(attn_partial, dim3(P_CHUNKS, BATCH), dim3(256), 0, stream,
                       input, semi, pacc, pm, pl, h, cat, cnt);
    // 3) out = tanh(cat @ Wo.T)  (K=2048, Dout=1024)
    hipLaunchKernelGGL(gemm_skinny, dim3(256), dim3(256), 0, stream,
                       cat, Wo, out, 2048, 1024, 1, (unsigned*)nullptr);
}

// Round 6
// 412.981 us; speedup vs baseline: 1.4165x; 1.4165x over previous
//
#include <hip/hip_runtime.h>
#include <math.h>

// Problem constants (S, B, D from reference).
#define S_LEN    2048
#define BATCH    32
#define DIM      1024
#define P_CHUNKS 32                 // seq chunks (blocks per batch)
#define CHUNK    (S_LEN / P_CHUNKS) // 64 rows per block
#define ROWS_PER_WAVE (CHUNK / 4)   // 16 rows per wave

// ---------------------------------------------------------------------------
// Skinny GEMM: out[b][d] = act( sum_k A[b][k] * W[d][k] ), b in [0,32).
// One wave per output column d (4 waves/block -> grid = Dout/4 blocks).
// A (32 x K) is staged in LDS in 256-wide K tiles, double-buffered; the
// next tile's staging registers AND the next W fragment are prefetched
// during compute so global loads stay in flight across the barrier.
// act: 0 = identity, 1 = tanh.
// ---------------------------------------------------------------------------
__global__ __launch_bounds__(256) void gemm_skinny(
    const float* __restrict__ A, const float* __restrict__ W,
    float* __restrict__ out, int K, int Dout, int act)
{
    __shared__ __align__(16) float At[2][32 * 256];  // 2 x 32 KiB

    const int t    = threadIdx.x;
    const int lane = t & 63;
    const int wid  = t >> 6;
    const int d    = blockIdx.x * 4 + wid;

    float acc[32];
#pragma unroll
    for (int b = 0; b < 32; ++b) acc[b] = 0.0f;

    // Preload tile 0 staging regs + this wave's W fragment for tile 0.
    float4 sreg[8];
#pragma unroll
    for (int i = 0; i < 8; ++i) {
        int f4id = t + i * 256;
        int bb   = f4id >> 6;       // row (batch)
        int c4   = f4id & 63;       // float4 column within tile
        sreg[i] = ((const float4*)(A + (size_t)bb * K))[c4];
    }
    float4 w4 = ((const float4*)(W + (size_t)d * K))[lane];

    int buf = 0;
    for (int k0 = 0; k0 < K; k0 += 256) {
        // Commit staged regs into LDS[buf].
#pragma unroll
        for (int i = 0; i < 8; ++i) {
            int f4id = t + i * 256;
            int bb   = f4id >> 6;
            int c4   = f4id & 63;
            ((float4*)At[buf])[bb * 64 + c4] = sreg[i];
        }
        __syncthreads();

        float4 w4c = w4;
        // Prefetch next tile (regs + W) while we compute this one.
        if (k0 + 256 < K) {
            const int k1 = k0 + 256;
#pragma unroll
            for (int i = 0; i < 8; ++i) {
                int f4id = t + i * 256;
                int bb   = f4id >> 6;
                int c4   = f4id & 63;
                sreg[i] = ((const float4*)(A + (size_t)bb * K + k1))[c4];
            }
            w4 = ((const float4*)(W + (size_t)d * K + k1))[lane];
        }

#pragma unroll
        for (int b = 0; b < 32; ++b) {
            float4 a4 = ((const float4*)At[buf])[b * 64 + lane];
            acc[b] = fmaf(w4c.x, a4.x, acc[b]);
            acc[b] = fmaf(w4c.y, a4.y, acc[b]);
            acc[b] = fmaf(w4c.z, a4.z, acc[b]);
            acc[b] = fmaf(w4c.w, a4.w, acc[b]);
        }
        buf ^= 1;
        // Single barrier per tile is safe: iteration i+1 writes the OTHER
        // buffer, and barrier_i guarantees all waves finished reading it.
    }

    // Reduce each acc[b] across the 64 lanes; lane b keeps batch b's result.
    float mine = 0.0f;
#pragma unroll
    for (int b = 0; b < 32; ++b) {
        float v = acc[b];
#pragma unroll
        for (int off = 32; off > 0; off >>= 1) v += __shfl_xor(v, off, 64);
        if (lane == b) mine = v;
    }
    if (lane < 32) {
        float o = act ? tanhf(mine) : mine;
        out[(size_t)lane * Dout + d] = o;
    }
}

// ---------------------------------------------------------------------------
// Flash-style fused logits + online softmax + weighted-sum partials.
// Each of the 4 waves owns 16 seq rows and the full 1024-wide feature dim
// (4 x float4 per lane); dot reduce is 6 in-wave shuffles, no barriers in
// the hot loop. Defer-rescale (THR=8): the post-reduce logit is wave-
// uniform, so the rescale branch is uniform and rare; P-terms are bounded
// by e^8 which f32 accumulation tolerates (renormalized at combine).
// The 4 wave-partials are merged in LDS at block end -> ONE partial
// (m, l, acc[1024]) per (b, chunk): pacc traffic drops 4x vs per-wave.
//
// NOTE (round-4 post-mortem): do NOT add a min-waves launch bound or a
// fence/atomic epilogue phase here. Both pushed the register allocator to
// 52 VGPRs, which killed the 4-deep float4 prefetch (loads sank to point
// of use -> latency-bound, 280 us, VALUBusy 2%). The hot loop NEEDS ~100
// VGPRs to hold prefetch + current row + semi + acc live.
// ---------------------------------------------------------------------------
__global__ __launch_bounds__(256) void attn_partial(
    const float* __restrict__ input, const float* __restrict__ semi,
    float* __restrict__ pacc, float* __restrict__ pm, float* __restrict__ pl)
{
    const int p    = blockIdx.x;   // seq chunk
    const int b    = blockIdx.y;   // batch
    const int t    = threadIdx.x;
    const int lane = t & 63;
    const int w    = t >> 6;
    const int s0   = p * CHUNK + w * ROWS_PER_WAVE;

    __shared__ __align__(16) float accs[4][DIM];   // 16 KiB
    __shared__ float smw[4], slw[4];

    // semi[b] fragment: 4 float4 per lane covering all 1024 features.
    const float4* sp = (const float4*)(semi + (size_t)b * DIM);
    const float4 sm0 = sp[lane];
    const float4 sm1 = sp[lane + 64];
    const float4 sm2 = sp[lane + 128];
    const float4 sm3 = sp[lane + 192];

    const float4* rp = (const float4*)(input + ((size_t)s0 * BATCH + b) * DIM);
    const size_t rstride = (size_t)BATCH * DIM / 4;  // 8192 float4 / seq row

    float m = -INFINITY, l = 0.0f;
    float4 a0 = make_float4(0.f, 0.f, 0.f, 0.f);
    float4 a1 = a0, a2 = a0, a3 = a0;

    // Prefetch row 0.
    float4 x0 = rp[lane], x1 = rp[lane + 64], x2 = rp[lane + 128], x3 = rp[lane + 192];

#pragma unroll 1
    for (int j = 0; j < ROWS_PER_WAVE; ++j) {
        const float4 c0 = x0, c1 = x1, c2 = x2, c3 = x3;
        if (j + 1 < ROWS_PER_WAVE) {
            const float4* np = rp + (size_t)(j + 1) * rstride;
            x0 = np[lane];       x1 = np[lane + 64];
            x2 = np[lane + 128]; x3 = np[lane + 192];
        }

        // 16-element partial dot for this lane.
        float pd = c0.x * sm0.x;
        pd = fmaf(c0.y, sm0.y, pd); pd = fmaf(c0.z, sm0.z, pd); pd = fmaf(c0.w, sm0.w, pd);
        pd = fmaf(c1.x, sm1.x, pd); pd = fmaf(c1.y, sm1.y, pd);
        pd = fmaf(c1.z, sm1.z, pd); pd = fmaf(c1.w, sm1.w, pd);
        pd = fmaf(c2.x, sm2.x, pd); pd = fmaf(c2.y, sm2.y, pd);
        pd = fmaf(c2.z, sm2.z, pd); pd = fmaf(c2.w, sm2.w, pd);
        pd = fmaf(c3.x, sm3.x, pd); pd = fmaf(c3.y, sm3.y, pd);
        pd = fmaf(c3.z, sm3.z, pd); pd = fmaf(c3.w, sm3.w, pd);

        // Full-wave butterfly: every lane ends with the row logit (uniform).
#pragma unroll
        for (int off = 32; off > 0; off >>= 1) pd += __shfl_xor(pd, off, 64);

        // Defer-rescale online softmax (wave-uniform branch).
        if (pd > m + 8.0f) {
            const float sc = __expf(m - pd);   // exp(-inf) = 0 on first row
            a0.x *= sc; a0.y *= sc; a0.z *= sc; a0.w *= sc;
            a1.x *= sc; a1.y *= sc; a1.z *= sc; a1.w *= sc;
            a2.x *= sc; a2.y *= sc; a2.z *= sc; a2.w *= sc;
            a3.x *= sc; a3.y *= sc; a3.z *= sc; a3.w *= sc;
            l *= sc;
            m = pd;
        }
        const float f = __expf(pd - m);        // bounded by e^8
        a0.x = fmaf(f, c0.x, a0.x); a0.y = fmaf(f, c0.y, a0.y);
        a0.z = fmaf(f, c0.z, a0.z); a0.w = fmaf(f, c0.w, a0.w);
        a1.x = fmaf(f, c1.x, a1.x); a1.y = fmaf(f, c1.y, a1.y);
        a1.z = fmaf(f, c1.z, a1.z); a1.w = fmaf(f, c1.w, a1.w);
        a2.x = fmaf(f, c2.x, a2.x); a2.y = fmaf(f, c2.y, a2.y);
        a2.z = fmaf(f, c2.z, a2.z); a2.w = fmaf(f, c2.w, a2.w);
        a3.x = fmaf(f, c3.x, a3.x); a3.y = fmaf(f, c3.y, a3.y);
        a3.z = fmaf(f, c3.z, a3.z); a3.w = fmaf(f, c3.w, a3.w);
        l += f;
    }

    // ---- block-level combine: 4 wave-partials -> 1 chunk-partial ----
    float4* as = (float4*)accs[w];
    as[lane]       = a0;
    as[lane + 64]  = a1;
    as[lane + 128] = a2;
    as[lane + 192] = a3;
    if (lane == 0) { smw[w] = m; slw[w] = l; }
    __syncthreads();

    const float M  = fmaxf(fmaxf(smw[0], smw[1]), fmaxf(smw[2], smw[3]));
    const float f0 = __expf(smw[0] - M);
    const float f1 = __expf(smw[1] - M);
    const float f2 = __expf(smw[2] - M);
    const float f3 = __expf(smw[3] - M);

    const float4 r0 = ((const float4*)accs[0])[t];
    const float4 r1 = ((const float4*)accs[1])[t];
    const float4 r2 = ((const float4*)accs[2])[t];
    const float4 r3 = ((const float4*)accs[3])[t];
    float4 o;
    o.x = fmaf(f3, r3.x, fmaf(f2, r2.x, fmaf(f1, r1.x, f0 * r0.x)));
    o.y = fmaf(f3, r3.y, fmaf(f2, r2.y, fmaf(f1, r1.y, f0 * r0.y)));
    o.z = fmaf(f3, r3.z, fmaf(f2, r2.z, fmaf(f1, r1.z, f0 * r0.z)));
    o.w = fmaf(f3, r3.w, fmaf(f2, r2.w, fmaf(f1, r1.w, f0 * r0.w)));

    ((float4*)(pacc + ((size_t)b * P_CHUNKS + p) * DIM))[t] = o;
    if (t == 0) {
        pm[b * P_CHUNKS + p] = M;
        pl[b * P_CHUNKS + p] =
            fmaf(f3, slw[3], fmaf(f2, slw[2], fmaf(f1, slw[1], f0 * slw[0])));
    }
}

// ---------------------------------------------------------------------------
// Combine 32 chunk-partials for batch b; write s_tilde into cat[:, :1024]
// and copy h into cat[:, 1024:]. Grid (32 batches x 4 d-quarters), 256 thr.
// ---------------------------------------------------------------------------
__global__ __launch_bounds__(256) void combine(
    const float* __restrict__ pacc, const float* __restrict__ pm,
    const float* __restrict__ pl, const float* __restrict__ h,
    float* __restrict__ cat)
{
    const int b = blockIdx.x;
    const int q = blockIdx.y;
    const int t = threadIdx.x;

    __shared__ float fsc[P_CHUNKS];
    __shared__ float Linv;

    if (t < 32) {
        const float mv = pm[b * P_CHUNKS + t];
        const float lv = pl[b * P_CHUNKS + t];
        float mx = mv;
#pragma unroll
        for (int off = 16; off > 0; off >>= 1)
            mx = fmaxf(mx, __shfl_xor(mx, off, 64));   // stays within lanes 0-31
        const float f = __expf(mv - mx);
        fsc[t] = f;
        float L = lv * f;
#pragma unroll
        for (int off = 16; off > 0; off >>= 1) L += __shfl_xor(L, off, 64);
        if (t == 0) Linv = 1.0f / L;
    }
    __syncthreads();

    const int d = q * 256 + t;
    const float* pb = pacc + (size_t)b * P_CHUNKS * DIM + d;
    float s0 = 0.f, s1 = 0.f, s2 = 0.f, s3 = 0.f;
#pragma unroll
    for (int pp = 0; pp < P_CHUNKS; pp += 4) {
        s0 = fmaf(fsc[pp + 0], pb[(size_t)(pp + 0) * DIM], s0);
        s1 = fmaf(fsc[pp + 1], pb[(size_t)(pp + 1) * DIM], s1);
        s2 = fmaf(fsc[pp + 2], pb[(size_t)(pp + 2) * DIM], s2);
        s3 = fmaf(fsc[pp + 3], pb[(size_t)(pp + 3) * DIM], s3);
    }
    const float sum = (s0 + s1) + (s2 + s3);

    cat[(size_t)b * (2 * DIM) + d]       = sum * Linv;
    cat[(size_t)b * (2 * DIM) + DIM + d] = h[(size_t)b * DIM + d];
}

// ---------------------------------------------------------------------------
extern "C" void kernel_launch(void* const* d_in, const int* in_sizes, int n_in,
                              void* d_out, int out_size, void* d_ws, size_t ws_size,
                              hipStream_t stream)
{
    const float* input = (const float*)d_in[0];  // [S, B, D]
    const float* h     = (const float*)d_in[1];  // [B, D]
    const float* Wi    = (const float*)d_in[2];  // [D, D]
    const float* Wo    = (const float*)d_in[3];  // [D, 2D]
    float* out = (float*)d_out;                  // [B, D]

    // Workspace carve (floats): semi | pacc | pm | pl | cat  (~4.4 MiB)
    float* ws   = (float*)d_ws;
    float* semi = ws;                                       // 32*1024
    float* pacc = semi + 32 * 1024;                         // 32*32*1024
    float* pm   = pacc + (size_t)32 * P_CHUNKS * 1024;      // 32*32
    float* pl   = pm + 32 * P_CHUNKS;                       // 32*32
    float* cat  = pl + 32 * P_CHUNKS;                       // 32*2048

    // 1) semi = h @ Wi.T   (K=1024, Dout=1024)
    hipLaunchKernelGGL(gemm_skinny, dim3(256), dim3(256), 0, stream,
                       h, Wi, semi, 1024, 1024, 0);
    // 2) fused logits + online softmax + weighted-sum partials (reads input once)
    hipLaunchKernelGGL(attn_partial, dim3(P_CHUNKS, BATCH), dim3(256), 0, stream,
                       input, semi, pacc, pm, pl);
    // 3) combine partials -> cat = [s_tilde, h]
    hipLaunchKernelGGL(combine, dim3(BATCH, 4), dim3(256), 0, stream,
                       pacc, pm, pl, h, cat);
    // 4) out = tanh(cat @ Wo.T)   (K=2048, Dout=1024)
    hipLaunchKernelGGL(gemm_skinny, dim3(256), dim3(256), 0, stream,
                       cat, Wo, out, 2048, 1024, 1);
}